// Round 3
// baseline (8812.254 us; speedup 1.0000x reference)
//
#include <hip/hip_runtime.h>

// Seq2Seq LSTM (B=2048, T=100, E=512, FUTURE=10, POSE=34). ALL inputs/outputs
// are FP32 (reference is jnp.float32; R0/R1 NaN came from misreading fp32 as
// bf16). Compute: bf16 MFMA with SPLIT WEIGHTS (W = W_hi + W_lo, two bf16
// planes) so weight rounding (systematic across 100 steps) is ~2^-17;
// h-state single bf16 (random per-step error), c-state fp32.
//   cell1 (enc): gates = bf16(x_t) @ M1^T (K=64 pad) + [h1|h1] @ [Whh1_hi|lo]^T + bias1
//   cell2 (enc): gates = [h1|h1]@[Wih2_hi|lo]^T + [h2|h2]@[Whh2_hi|lo]^T + bias2
//   dec step0  : gates = [h2|h2]@[dWhh_hi|lo]^T + biasd            (out=0)
//   dec step f : gates = [h|h]@[(dWih+dWhh)_hi|lo]^T + biasd       (out==h)
// Block = 256 thr (4 waves), tile = 64 batch-rows x 64 e-cols x 4 gates;
// i,f,g,o of one (b,e) land in the same lane/register -> per-lane epilogue.
// Decoder h dual-stored (bf16 for next GEMM, fp32 for exact out projection).

#define TSEQ 100
#define FUT 10
#define POSE_D 34
#define EDIM 512
#define BDIM 2048

typedef __bf16 bf16x8 __attribute__((ext_vector_type(8)));
typedef float floatx4 __attribute__((ext_vector_type(4)));
typedef short shortx8 __attribute__((ext_vector_type(8)));

__device__ __forceinline__ float bf2f(short s) {
    unsigned int u = ((unsigned int)(unsigned short)s) << 16;
    float f;
    __builtin_memcpy(&f, &u, 4);
    return f;
}
__device__ __forceinline__ short f2bf(float f) {
    unsigned int u;
    __builtin_memcpy(&u, &f, 4);
    u += 0x7fffu + ((u >> 16) & 1u);
    return (short)(u >> 16);
}
__device__ __forceinline__ float fsig(float x) { return 1.f / (1.f + __expf(-x)); }
__device__ __forceinline__ float ftanh(float x) {
    float ax = fabsf(x);
    float t = __expf(-2.f * ax);
    float r = (1.f - t) / (1.f + t);
    return x < 0.f ? -r : r;
}

// LDS layout (shorts): A tile [64][64] at 0; W tile gate g [64][64] at (1+g)*4096.
__device__ __forceinline__ void mfma_chunk(const short* lds, int tid, floatx4 (&acc)[4][4]) {
    const int lane = tid & 63;
    const int wv = tid >> 6;
    const int m = lane & 15;
    const int q = lane >> 4;
#pragma unroll
    for (int kk = 0; kk < 2; ++kk) {
        const int ko = kk * 32 + q * 8;
        bf16x8 a[4], b[4];
#pragma unroll
        for (int ri = 0; ri < 4; ++ri)
            a[ri] = *(const bf16x8*)(lds + (ri * 16 + m) * 64 + ko);
#pragma unroll
        for (int g = 0; g < 4; ++g)
            b[g] = *(const bf16x8*)(lds + (1 + g) * 4096 + (wv * 16 + m) * 64 + ko);
#pragma unroll
        for (int ri = 0; ri < 4; ++ri)
#pragma unroll
            for (int g = 0; g < 4; ++g)
                acc[ri][g] = __builtin_amdgcn_mfma_f32_16x16x32_bf16(a[ri], b[g], acc[ri][g], 0, 0, 0);
    }
}

// Split-K=1024 phase: gates += [h|h] @ [W_hi|W_lo]^T.
// A: bf16 [2048 x 512] (read twice); W: bf16 [2048 x 1024] (hi cols 0..511, lo 512..1023).
__device__ __forceinline__ void gemm_phase(const short* __restrict__ A,
                                           const short* __restrict__ W,
                                           short* lds, int tid, int R0, int E0,
                                           floatx4 (&acc)[4][4]) {
#pragma unroll 1
    for (int kc = 0; kc < 16; ++kc) {
        const int ka = (kc & 7) * 64;
        const int kw = kc * 64;
        shortx8 ra0, ra1, rw[8];
        ra0 = *(const shortx8*)(A + (long)(R0 + (tid >> 3)) * EDIM + ka + ((tid & 7) << 3));
        {
            const int u = tid + 256;
            ra1 = *(const shortx8*)(A + (long)(R0 + (u >> 3)) * EDIM + ka + ((u & 7) << 3));
        }
#pragma unroll
        for (int i = 0; i < 8; ++i) {
            const int v = tid + (i << 8);
            const int g = v >> 9, w = v & 511;
            rw[i] = *(const shortx8*)(W + (long)((g << 9) + E0 + (w >> 3)) * 1024 + kw + ((v & 7) << 3));
        }
        __syncthreads();  // previous mfma_chunk readers done before overwrite
        *(shortx8*)(lds + tid * 8) = ra0;
        *(shortx8*)(lds + (tid + 256) * 8) = ra1;
#pragma unroll
        for (int i = 0; i < 8; ++i)
            *(shortx8*)(lds + (512 + tid + (i << 8)) * 8) = rw[i];
        __syncthreads();
        mfma_chunk(lds, tid, acc);
    }
}

template <bool HAS_X, bool TWO_H>
__global__ __launch_bounds__(256) void lstm_cell_kernel(
    const float* __restrict__ xptr, const short* __restrict__ M1,
    const short* __restrict__ A1, const short* __restrict__ W1,
    const short* __restrict__ A2, const short* __restrict__ W2,
    const float* __restrict__ bias, float* __restrict__ c_io,
    short* __restrict__ h_out, float* __restrict__ hf_out) {
    __shared__ __align__(16) short lds[5 * 4096];
    const int tid = threadIdx.x;
    const int R0 = blockIdx.x * 64;
    const int E0 = blockIdx.y * 64;
    floatx4 acc[4][4];
#pragma unroll
    for (int ri = 0; ri < 4; ++ri)
#pragma unroll
        for (int g = 0; g < 4; ++g) acc[ri][g] = {0.f, 0.f, 0.f, 0.f};

    if (HAS_X) {
        // M1 tiles into registers (row stride 64 shorts)
        shortx8 rm[8];
#pragma unroll
        for (int i = 0; i < 8; ++i) {
            const int v = tid + (i << 8);
            const int g = v >> 9, w = v & 511;
            rm[i] = *(const shortx8*)(M1 + (long)((g << 9) + E0 + (w >> 3)) * 64 + ((v & 7) << 3));
        }
        // zero-fill A tile (K pad 34->64), then bf16-convert the fp32 x slice
        floatx4 z = {0.f, 0.f, 0.f, 0.f};
        *(floatx4*)(lds + tid * 8) = z;
        *(floatx4*)(lds + (tid + 256) * 8) = z;
        __syncthreads();
        for (int idx = tid; idx < 64 * POSE_D; idx += 256) {
            const int r = idx / POSE_D;
            const int c = idx - r * POSE_D;
            lds[r * 64 + c] = f2bf(xptr[(long)(R0 + r) * (TSEQ * POSE_D) + c]);
        }
#pragma unroll
        for (int i = 0; i < 8; ++i)
            *(shortx8*)(lds + (512 + tid + (i << 8)) * 8) = rm[i];
        __syncthreads();
        mfma_chunk(lds, tid, acc);
    }

    gemm_phase(A1, W1, lds, tid, R0, E0, acc);
    if (TWO_H) gemm_phase(A2, W2, lds, tid, R0, E0, acc);

    // ---- fused LSTM pointwise epilogue (per-lane: i,f,g,o share lane/reg) ----
    const int lane = tid & 63;
    const int wv = tid >> 6;
    const int m = lane & 15;
    const int q = lane >> 4;
    const int e = E0 + wv * 16 + m;
    const float bi = bias[e];
    const float bfv = bias[512 + e];
    const float bg = bias[1024 + e];
    const float bo = bias[1536 + e];
#pragma unroll
    for (int ri = 0; ri < 4; ++ri) {
#pragma unroll
        for (int rg = 0; rg < 4; ++rg) {
            const int br = R0 + ri * 16 + q * 4 + rg;  // C/D: row=q*4+reg, col=lane&15
            const long cidx = (long)br * EDIM + e;
            const float iv = fsig(acc[ri][0][rg] + bi);
            const float fv = fsig(acc[ri][1][rg] + bfv);
            const float gv = ftanh(acc[ri][2][rg] + bg);
            const float ov = fsig(acc[ri][3][rg] + bo);
            const float cn = fv * c_io[cidx] + iv * gv;
            c_io[cidx] = cn;
            const float hv = ov * ftanh(cn);
            h_out[cidx] = f2bf(hv);
            if (hf_out) hf_out[cidx] = hv;
        }
    }
}

__global__ __launch_bounds__(256) void zero_kernel(unsigned int* __restrict__ p, int n) {
    int i = blockIdx.x * 256 + threadIdx.x;
    const int stride = gridDim.x * 256;
    for (; i < n; i += stride) p[i] = 0u;
}

// bias1 = bih1 + bhh1 + Wih1 @ enc_lin_b ; bias2 = bih2+bhh2 ; biasd = dbih+dbhh
__global__ __launch_bounds__(256) void prep_bias(
    const float* __restrict__ bih1, const float* __restrict__ bhh1,
    const float* __restrict__ Wih1, const float* __restrict__ encb,
    const float* __restrict__ bih2, const float* __restrict__ bhh2,
    const float* __restrict__ dbih, const float* __restrict__ dbhh,
    float* __restrict__ bias1, float* __restrict__ bias2, float* __restrict__ biasd) {
    const int n = blockIdx.x * 256 + threadIdx.x;
    if (n >= 2048) return;
    float s = bih1[n] + bhh1[n];
    const float* wr = Wih1 + (long)n * EDIM;
    for (int j = 0; j < EDIM; ++j) s += wr[j] * encb[j];
    bias1[n] = s;
    bias2[n] = bih2[n] + bhh2[n];
    biasd[n] = dbih[n] + dbhh[n];
}

// M1[n][k] = sum_j Wih1[n][j] * enc_lin_W[j][k] (k<34, else 0), bf16 [2048 x 64]
__global__ __launch_bounds__(256) void prep_M1(const float* __restrict__ Wih1,
                                               const float* __restrict__ encW,
                                               short* __restrict__ M1) {
    const int idx = blockIdx.x * 256 + threadIdx.x;
    if (idx >= 2048 * 64) return;
    const int n = idx >> 6, k = idx & 63;
    float s = 0.f;
    if (k < POSE_D) {
        const float* wr = Wih1 + (long)n * EDIM;
        for (int j = 0; j < EDIM; ++j) s += wr[j] * encW[j * POSE_D + k];
    }
    M1[idx] = f2bf(s);
}

// Split fp32 W[2048x512] (+optional second addend) into bf16 hi|lo planes [2048x1024]
__global__ __launch_bounds__(256) void split_w(const float* __restrict__ a,
                                               const float* __restrict__ b,
                                               short* __restrict__ o) {
    const int i = blockIdx.x * 256 + threadIdx.x;
    if (i >= 2048 * EDIM) return;
    const int r = i >> 9, c = i & 511;
    const float v = b ? (a[i] + b[i]) : a[i];
    const short hi = f2bf(v);
    o[(long)r * 1024 + c] = hi;
    o[(long)r * 1024 + 512 + c] = f2bf(v - bf2f(hi));
}

// out[b,f,p] = hf[b,:] . dec_lin_W[p,:] + dec_lin_b[p]  (pure fp32)
__global__ __launch_bounds__(64) void out_proj(const float* __restrict__ hf,
                                               const float* __restrict__ W,
                                               const float* __restrict__ bias,
                                               float* __restrict__ out, int f) {
    const int b = blockIdx.x;
    __shared__ float hrow[EDIM];
    const int lane = threadIdx.x;
    *(floatx4*)(hrow + lane * 8) = *(const floatx4*)(hf + (long)b * EDIM + lane * 8);
    *(floatx4*)(hrow + lane * 8 + 4) = *(const floatx4*)(hf + (long)b * EDIM + lane * 8 + 4);
    __syncthreads();
    if (lane < POSE_D) {
        float acc = bias[lane];
        const float* wr = W + (long)lane * EDIM;
        for (int e = 0; e < EDIM; e += 4) {
            const floatx4 wv = *(const floatx4*)(wr + e);
            acc += hrow[e] * wv[0] + hrow[e + 1] * wv[1] + hrow[e + 2] * wv[2] + hrow[e + 3] * wv[3];
        }
        out[((long)b * FUT + f) * POSE_D + lane] = acc;
    }
}

extern "C" void kernel_launch(void* const* d_in, const int* in_sizes, int n_in,
                              void* d_out, int out_size, void* d_ws, size_t ws_size,
                              hipStream_t stream) {
    const float* x = (const float*)d_in[0];
    const float* encW = (const float*)d_in[1];
    const float* encb = (const float*)d_in[2];
    const float* Wih1 = (const float*)d_in[3];
    const float* Whh1 = (const float*)d_in[4];
    const float* bih1 = (const float*)d_in[5];
    const float* bhh1 = (const float*)d_in[6];
    const float* Wih2 = (const float*)d_in[7];
    const float* Whh2 = (const float*)d_in[8];
    const float* bih2 = (const float*)d_in[9];
    const float* bhh2 = (const float*)d_in[10];
    const float* dWih = (const float*)d_in[11];
    const float* dWhh = (const float*)d_in[12];
    const float* dbih = (const float*)d_in[13];
    const float* dbhh = (const float*)d_in[14];
    const float* oW = (const float*)d_in[15];
    const float* ob = (const float*)d_in[16];
    float* out = (float*)d_out;

    char* ws = (char*)d_ws;
    size_t off = 0;
    auto alloc = [&](size_t bytes) -> char* {
        char* p = ws + off;
        off = (off + bytes + 255) & ~(size_t)255;
        return p;
    };
    const size_t HB = (size_t)BDIM * EDIM * 2;   // 2 MB bf16 state
    const size_t CB = (size_t)BDIM * EDIM * 4;   // 4 MB fp32 state
    const size_t WSP = (size_t)2048 * 1024 * 2;  // 4 MB split-weight plane-pair
    // zero-region (contiguous): h1_0, h2_0, c1, c2
    short* h1_0 = (short*)alloc(HB);
    short* h2_0 = (short*)alloc(HB);
    float* c1 = (float*)alloc(CB);
    float* c2 = (float*)alloc(CB);
    short* h1_1 = (short*)alloc(HB);
    short* h2_1 = (short*)alloc(HB);
    float* hf0 = (float*)alloc(CB);
    float* hf1 = (float*)alloc(CB);
    short* M1 = (short*)alloc((size_t)2048 * 64 * 2);
    short* sWhh1 = (short*)alloc(WSP);
    short* sWih2 = (short*)alloc(WSP);
    short* sWhh2 = (short*)alloc(WSP);
    short* sdWhh = (short*)alloc(WSP);
    short* sWsum = (short*)alloc(WSP);
    float* bias1 = (float*)alloc(2048 * 4);
    float* bias2 = (float*)alloc(2048 * 4);
    float* biasd = (float*)alloc(2048 * 4);
    (void)ws_size; (void)in_sizes; (void)n_in; (void)out_size;

    zero_kernel<<<2048, 256, 0, stream>>>((unsigned int*)h1_0, (int)((2 * HB + 2 * CB) / 4));
    prep_bias<<<8, 256, 0, stream>>>(bih1, bhh1, Wih1, encb, bih2, bhh2, dbih, dbhh,
                                     bias1, bias2, biasd);
    prep_M1<<<512, 256, 0, stream>>>(Wih1, encW, M1);
    split_w<<<4096, 256, 0, stream>>>(Whh1, nullptr, sWhh1);
    split_w<<<4096, 256, 0, stream>>>(Wih2, nullptr, sWih2);
    split_w<<<4096, 256, 0, stream>>>(Whh2, nullptr, sWhh2);
    split_w<<<4096, 256, 0, stream>>>(dWhh, nullptr, sdWhh);
    split_w<<<4096, 256, 0, stream>>>(dWih, dWhh, sWsum);

    dim3 grid(32, 8), blk(256);
    short *h1p = h1_0, *h1n = h1_1, *h2p = h2_0, *h2n = h2_1;
    for (int t = 0; t < TSEQ; ++t) {
        lstm_cell_kernel<true, false><<<grid, blk, 0, stream>>>(
            x + t * POSE_D, M1, h1p, sWhh1, nullptr, nullptr,
            bias1, c1, h1n, nullptr);
        lstm_cell_kernel<false, true><<<grid, blk, 0, stream>>>(
            nullptr, nullptr, h1n, sWih2, h2p, sWhh2,
            bias2, c2, h2n, nullptr);
        short* t1 = h1p; h1p = h1n; h1n = t1;
        short* t2 = h2p; h2p = h2n; h2n = t2;
    }
    // decoder: bf16 h ping-pong reuses freed h1 buffers; fp32 copy for out_proj
    short* hd0 = h1_1;
    short* hd1 = h1_0;
    lstm_cell_kernel<false, false><<<grid, blk, 0, stream>>>(
        nullptr, nullptr, h2p, sdWhh, nullptr, nullptr,
        biasd, c2, hd0, hf0);
    out_proj<<<BDIM, 64, 0, stream>>>(hf0, oW, ob, out, 0);
    short *dp = hd0, *dn = hd1;
    float *fp = hf0, *fn = hf1;
    for (int f = 1; f < FUT; ++f) {
        lstm_cell_kernel<false, false><<<grid, blk, 0, stream>>>(
            nullptr, nullptr, dp, sWsum, nullptr, nullptr,
            biasd, c2, dn, fn);
        out_proj<<<BDIM, 64, 0, stream>>>(fn, oW, ob, out, f);
        short* tt = dp; dp = dn; dn = tt;
        float* tf = fp; fp = fn; fn = tf;
    }
}

// Round 4
// 6410.388 us; speedup vs baseline: 1.3747x; 1.3747x over previous
//
#include <hip/hip_runtime.h>

// Seq2Seq LSTM (B=2048, T=100, E=512, FUTURE=10, POSE=34). FP32 in/out.
// Compute: bf16 MFMA, SPLIT WEIGHTS (W = W_hi + W_lo bf16 planes, K=1024),
// h-state bf16, c-state fp32.
//   cell1 (enc): gates = bf16(x_t)@M1^T (K=64 pad) + [h1|h1]@[Whh1_hi|lo]^T + bias1
//   cell2 (enc): gates = [h1|h1]@[Wih2_hi|lo]^T + [h2|h2]@[Whh2_hi|lo]^T + bias2
//   dec step0  : gates = [h2|h2]@[dWhh_hi|lo]^T + biasd            (out=0)
//   dec step f : gates = [h|h]@[(dWih+dWhh)_hi|lo]^T + biasd       (out==h)
// Block = 256 thr (4 waves), tile = 64 batch-rows x 64 e-cols x 4 gates;
// i,f,g,o of one (b,e) share a lane/register -> per-lane pointwise epilogue.
// R3: XOR-swizzled LDS (kills 16-lane-per-4-bank read conflicts, 6.29M/disp
// measured in R2) + double-buffered LDS with 1 barrier/chunk and global
// prefetch of chunk k+1 overlapping MFMA of chunk k.

#define TSEQ 100
#define FUT 10
#define POSE_D 34
#define EDIM 512
#define BDIM 2048
#define BUFS 20480  // shorts per LDS buffer: A 4096 + 4 gates * 4096

typedef __bf16 bf16x8 __attribute__((ext_vector_type(8)));
typedef float floatx4 __attribute__((ext_vector_type(4)));
typedef short shortx8 __attribute__((ext_vector_type(8)));

__device__ __forceinline__ float bf2f(short s) {
    unsigned int u = ((unsigned int)(unsigned short)s) << 16;
    float f;
    __builtin_memcpy(&f, &u, 4);
    return f;
}
__device__ __forceinline__ short f2bf(float f) {
    unsigned int u;
    __builtin_memcpy(&u, &f, 4);
    u += 0x7fffu + ((u >> 16) & 1u);
    return (short)(u >> 16);
}
__device__ __forceinline__ float fsig(float x) { return 1.f / (1.f + __expf(-x)); }
__device__ __forceinline__ float ftanh(float x) {
    float ax = fabsf(x);
    float t = __expf(-2.f * ax);
    float r = (1.f - t) / (1.f + t);
    return x < 0.f ? -r : r;
}

// Swizzled offset (shorts) of 16B unit (row r, col c) within a [64 x 8-unit] tile.
__device__ __forceinline__ int swz(int r, int c) { return r * 64 + ((c ^ (r & 7)) << 3); }

// Fragment reads from swizzled layout. Bank = ((kk*4+q)^(m&7))*4 -> all 32
// banks, 2 lanes each = b128 floor, no conflicts.
__device__ __forceinline__ void mfma_chunk(const short* buf, int tid, floatx4 (&acc)[4][4]) {
    const int lane = tid & 63;
    const int wv = tid >> 6;
    const int m = lane & 15;
    const int q = lane >> 4;
    const int sw = m & 7;
#pragma unroll
    for (int kk = 0; kk < 2; ++kk) {
        const int cx = ((kk * 4 + q) ^ sw) << 3;
        bf16x8 a[4], b[4];
#pragma unroll
        for (int ri = 0; ri < 4; ++ri)
            a[ri] = *(const bf16x8*)(buf + (ri * 16 + m) * 64 + cx);
#pragma unroll
        for (int g = 0; g < 4; ++g)
            b[g] = *(const bf16x8*)(buf + (1 + g) * 4096 + (wv * 16 + m) * 64 + cx);
#pragma unroll
        for (int ri = 0; ri < 4; ++ri)
#pragma unroll
            for (int g = 0; g < 4; ++g)
                acc[ri][g] = __builtin_amdgcn_mfma_f32_16x16x32_bf16(a[ri], b[g], acc[ri][g], 0, 0, 0);
    }
}

template <bool HAS_X, bool TWO_H>
__global__ __launch_bounds__(256) void lstm_cell_kernel(
    const float* __restrict__ xptr, const short* __restrict__ M1,
    const short* __restrict__ A1, const short* __restrict__ W1,
    const short* __restrict__ A2, const short* __restrict__ W2,
    const float* __restrict__ bias, float* __restrict__ c_io,
    short* __restrict__ h_out, float* __restrict__ hf_out) {
    __shared__ __align__(16) short lds[2 * BUFS];
    const int tid = threadIdx.x;
    const int R0 = blockIdx.x * 64;
    const int E0 = blockIdx.y * 64;
    floatx4 acc[4][4];
#pragma unroll
    for (int ri = 0; ri < 4; ++ri)
#pragma unroll
        for (int g = 0; g < 4; ++g) acc[ri][g] = {0.f, 0.f, 0.f, 0.f};

    shortx8 ra0, ra1, rw[8];

    // Load chunk kc's A+W slices into registers (global/L2 -> VGPR).
    auto load_chunk = [&](int kc) {
        const short* A = (TWO_H && kc >= 16) ? A2 : A1;
        const short* W = (TWO_H && kc >= 16) ? W2 : W1;
        const int ka = (kc & 7) * 64;    // A is K=512, read for both planes
        const int kw = (kc & 15) * 64;   // W is K=1024 (hi|lo)
        ra0 = *(const shortx8*)(A + (long)(R0 + (tid >> 3)) * EDIM + ka + ((tid & 7) << 3));
        {
            const int u = tid + 256;
            ra1 = *(const shortx8*)(A + (long)(R0 + (u >> 3)) * EDIM + ka + ((u & 7) << 3));
        }
#pragma unroll
        for (int i = 0; i < 8; ++i) {
            const int v = tid + (i << 8);
            const int g = v >> 9, w = v & 511;
            rw[i] = *(const shortx8*)(W + (long)((g << 9) + E0 + (w >> 3)) * 1024 + kw + ((v & 7) << 3));
        }
    };
    // Store registers to swizzled LDS buffer (write banks at b128 floor).
    auto store_chunk = [&](short* buf) {
        *(shortx8*)(buf + swz(tid >> 3, tid & 7)) = ra0;
        {
            const int u = tid + 256;
            *(shortx8*)(buf + swz(u >> 3, u & 7)) = ra1;
        }
#pragma unroll
        for (int i = 0; i < 8; ++i) {
            const int v = tid + (i << 8);
            const int g = v >> 9, w = v & 511;
            *(shortx8*)(buf + (1 + g) * 4096 + swz(w >> 3, w & 7)) = rw[i];
        }
    };

    const int NCH = TWO_H ? 32 : 16;

    if (HAS_X) {
        // x-chunk = pipeline stage -1, staged in buf1 (parity consistent).
        short* buf1 = lds + BUFS;
        floatx4 z = {0.f, 0.f, 0.f, 0.f};
        *(floatx4*)(buf1 + swz(tid >> 3, tid & 7)) = z;
        {
            const int u = tid + 256;
            *(floatx4*)(buf1 + swz(u >> 3, u & 7)) = z;
        }
        __syncthreads();  // zero-fill visible before scalar x overwrites
#pragma unroll
        for (int i = 0; i < 8; ++i) {  // M1 tiles (row stride 64 shorts) -> regs
            const int v = tid + (i << 8);
            const int g = v >> 9, w = v & 511;
            rw[i] = *(const shortx8*)(M1 + (long)((g << 9) + E0 + (w >> 3)) * 64 + ((v & 7) << 3));
        }
        for (int idx = tid; idx < 64 * POSE_D; idx += 256) {
            const int r = idx / POSE_D;
            const int c = idx - r * POSE_D;
            buf1[swz(r, c >> 3) + (c & 7)] = f2bf(xptr[(long)(R0 + r) * (TSEQ * POSE_D) + c]);
        }
#pragma unroll
        for (int i = 0; i < 8; ++i) {
            const int v = tid + (i << 8);
            const int g = v >> 9, w = v & 511;
            *(shortx8*)(buf1 + (1 + g) * 4096 + swz(w >> 3, w & 7)) = rw[i];
        }
        __syncthreads();
        load_chunk(0);            // chunk-0 global loads fly during x-MFMA
        mfma_chunk(buf1, tid, acc);
    } else {
        load_chunk(0);
    }

#pragma unroll 1
    for (int kc = 0; kc < NCH; ++kc) {
        short* buf = lds + (kc & 1) * BUFS;
        store_chunk(buf);                     // waits vmcnt for kc's loads
        if (kc + 1 < NCH) load_chunk(kc + 1); // prefetch overlaps MFMA below
        __syncthreads();
        mfma_chunk(buf, tid, acc);
        // buf[(kc)&1] safe to rewrite at kc+2: this barrier + lgkm drain at
        // barrier kc+1 orders all reads before those writes.
    }

    // ---- fused LSTM pointwise epilogue (per-lane: i,f,g,o share lane/reg) ----
    const int lane = tid & 63;
    const int wv = tid >> 6;
    const int m = lane & 15;
    const int q = lane >> 4;
    const int e = E0 + wv * 16 + m;
    const float bi = bias[e];
    const float bfv = bias[512 + e];
    const float bg = bias[1024 + e];
    const float bo = bias[1536 + e];
#pragma unroll
    for (int ri = 0; ri < 4; ++ri) {
#pragma unroll
        for (int rg = 0; rg < 4; ++rg) {
            const int br = R0 + ri * 16 + q * 4 + rg;  // C/D: row=q*4+reg, col=lane&15
            const long cidx = (long)br * EDIM + e;
            const float iv = fsig(acc[ri][0][rg] + bi);
            const float fv = fsig(acc[ri][1][rg] + bfv);
            const float gv = ftanh(acc[ri][2][rg] + bg);
            const float ov = fsig(acc[ri][3][rg] + bo);
            const float cn = fv * c_io[cidx] + iv * gv;
            c_io[cidx] = cn;
            const float hv = ov * ftanh(cn);
            h_out[cidx] = f2bf(hv);
            if (hf_out) hf_out[cidx] = hv;
        }
    }
}

__global__ __launch_bounds__(256) void zero_kernel(unsigned int* __restrict__ p, int n) {
    int i = blockIdx.x * 256 + threadIdx.x;
    const int stride = gridDim.x * 256;
    for (; i < n; i += stride) p[i] = 0u;
}

// bias1 = bih1 + bhh1 + Wih1 @ enc_lin_b ; bias2 = bih2+bhh2 ; biasd = dbih+dbhh
__global__ __launch_bounds__(256) void prep_bias(
    const float* __restrict__ bih1, const float* __restrict__ bhh1,
    const float* __restrict__ Wih1, const float* __restrict__ encb,
    const float* __restrict__ bih2, const float* __restrict__ bhh2,
    const float* __restrict__ dbih, const float* __restrict__ dbhh,
    float* __restrict__ bias1, float* __restrict__ bias2, float* __restrict__ biasd) {
    const int n = blockIdx.x * 256 + threadIdx.x;
    if (n >= 2048) return;
    float s = bih1[n] + bhh1[n];
    const float* wr = Wih1 + (long)n * EDIM;
    for (int j = 0; j < EDIM; ++j) s += wr[j] * encb[j];
    bias1[n] = s;
    bias2[n] = bih2[n] + bhh2[n];
    biasd[n] = dbih[n] + dbhh[n];
}

// M1[n][k] = sum_j Wih1[n][j] * enc_lin_W[j][k] (k<34, else 0), bf16 [2048 x 64]
__global__ __launch_bounds__(256) void prep_M1(const float* __restrict__ Wih1,
                                               const float* __restrict__ encW,
                                               short* __restrict__ M1) {
    const int idx = blockIdx.x * 256 + threadIdx.x;
    if (idx >= 2048 * 64) return;
    const int n = idx >> 6, k = idx & 63;
    float s = 0.f;
    if (k < POSE_D) {
        const float* wr = Wih1 + (long)n * EDIM;
        for (int j = 0; j < EDIM; ++j) s += wr[j] * encW[j * POSE_D + k];
    }
    M1[idx] = f2bf(s);
}

// Split fp32 W[2048x512] (+optional second addend) into bf16 hi|lo planes [2048x1024]
__global__ __launch_bounds__(256) void split_w(const float* __restrict__ a,
                                               const float* __restrict__ b,
                                               short* __restrict__ o) {
    const int i = blockIdx.x * 256 + threadIdx.x;
    if (i >= 2048 * EDIM) return;
    const int r = i >> 9, c = i & 511;
    const float v = b ? (a[i] + b[i]) : a[i];
    const short hi = f2bf(v);
    o[(long)r * 1024 + c] = hi;
    o[(long)r * 1024 + 512 + c] = f2bf(v - bf2f(hi));
}

// out[b,f,p] = hf[b,:] . dec_lin_W[p,:] + dec_lin_b[p]  (pure fp32)
__global__ __launch_bounds__(64) void out_proj(const float* __restrict__ hf,
                                               const float* __restrict__ W,
                                               const float* __restrict__ bias,
                                               float* __restrict__ out, int f) {
    const int b = blockIdx.x;
    __shared__ float hrow[EDIM];
    const int lane = threadIdx.x;
    *(floatx4*)(hrow + lane * 8) = *(const floatx4*)(hf + (long)b * EDIM + lane * 8);
    *(floatx4*)(hrow + lane * 8 + 4) = *(const floatx4*)(hf + (long)b * EDIM + lane * 8 + 4);
    __syncthreads();
    if (lane < POSE_D) {
        float acc = bias[lane];
        const float* wr = W + (long)lane * EDIM;
        for (int e = 0; e < EDIM; e += 4) {
            const floatx4 wv = *(const floatx4*)(wr + e);
            acc += hrow[e] * wv[0] + hrow[e + 1] * wv[1] + hrow[e + 2] * wv[2] + hrow[e + 3] * wv[3];
        }
        out[((long)b * FUT + f) * POSE_D + lane] = acc;
    }
}

extern "C" void kernel_launch(void* const* d_in, const int* in_sizes, int n_in,
                              void* d_out, int out_size, void* d_ws, size_t ws_size,
                              hipStream_t stream) {
    const float* x = (const float*)d_in[0];
    const float* encW = (const float*)d_in[1];
    const float* encb = (const float*)d_in[2];
    const float* Wih1 = (const float*)d_in[3];
    const float* Whh1 = (const float*)d_in[4];
    const float* bih1 = (const float*)d_in[5];
    const float* bhh1 = (const float*)d_in[6];
    const float* Wih2 = (const float*)d_in[7];
    const float* Whh2 = (const float*)d_in[8];
    const float* bih2 = (const float*)d_in[9];
    const float* bhh2 = (const float*)d_in[10];
    const float* dWih = (const float*)d_in[11];
    const float* dWhh = (const float*)d_in[12];
    const float* dbih = (const float*)d_in[13];
    const float* dbhh = (const float*)d_in[14];
    const float* oW = (const float*)d_in[15];
    const float* ob = (const float*)d_in[16];
    float* out = (float*)d_out;

    char* ws = (char*)d_ws;
    size_t off = 0;
    auto alloc = [&](size_t bytes) -> char* {
        char* p = ws + off;
        off = (off + bytes + 255) & ~(size_t)255;
        return p;
    };
    const size_t HB = (size_t)BDIM * EDIM * 2;   // 2 MB bf16 state
    const size_t CB = (size_t)BDIM * EDIM * 4;   // 4 MB fp32 state
    const size_t WSP = (size_t)2048 * 1024 * 2;  // 4 MB split-weight plane-pair
    // zero-region (contiguous): h1_0, h2_0, c1, c2
    short* h1_0 = (short*)alloc(HB);
    short* h2_0 = (short*)alloc(HB);
    float* c1 = (float*)alloc(CB);
    float* c2 = (float*)alloc(CB);
    short* h1_1 = (short*)alloc(HB);
    short* h2_1 = (short*)alloc(HB);
    float* hf0 = (float*)alloc(CB);
    float* hf1 = (float*)alloc(CB);
    short* M1 = (short*)alloc((size_t)2048 * 64 * 2);
    short* sWhh1 = (short*)alloc(WSP);
    short* sWih2 = (short*)alloc(WSP);
    short* sWhh2 = (short*)alloc(WSP);
    short* sdWhh = (short*)alloc(WSP);
    short* sWsum = (short*)alloc(WSP);
    float* bias1 = (float*)alloc(2048 * 4);
    float* bias2 = (float*)alloc(2048 * 4);
    float* biasd = (float*)alloc(2048 * 4);
    (void)ws_size; (void)in_sizes; (void)n_in; (void)out_size;

    zero_kernel<<<2048, 256, 0, stream>>>((unsigned int*)h1_0, (int)((2 * HB + 2 * CB) / 4));
    prep_bias<<<8, 256, 0, stream>>>(bih1, bhh1, Wih1, encb, bih2, bhh2, dbih, dbhh,
                                     bias1, bias2, biasd);
    prep_M1<<<512, 256, 0, stream>>>(Wih1, encW, M1);
    split_w<<<4096, 256, 0, stream>>>(Whh1, nullptr, sWhh1);
    split_w<<<4096, 256, 0, stream>>>(Wih2, nullptr, sWih2);
    split_w<<<4096, 256, 0, stream>>>(Whh2, nullptr, sWhh2);
    split_w<<<4096, 256, 0, stream>>>(dWhh, nullptr, sdWhh);
    split_w<<<4096, 256, 0, stream>>>(dWih, dWhh, sWsum);

    dim3 grid(32, 8), blk(256);
    short *h1p = h1_0, *h1n = h1_1, *h2p = h2_0, *h2n = h2_1;
    for (int t = 0; t < TSEQ; ++t) {
        lstm_cell_kernel<true, false><<<grid, blk, 0, stream>>>(
            x + t * POSE_D, M1, h1p, sWhh1, nullptr, nullptr,
            bias1, c1, h1n, nullptr);
        lstm_cell_kernel<false, true><<<grid, blk, 0, stream>>>(
            nullptr, nullptr, h1n, sWih2, h2p, sWhh2,
            bias2, c2, h2n, nullptr);
        short* t1 = h1p; h1p = h1n; h1n = t1;
        short* t2 = h2p; h2p = h2n; h2n = t2;
    }
    // decoder: bf16 h ping-pong reuses freed h1 buffers; fp32 copy for out_proj
    short* hd0 = h1_1;
    short* hd1 = h1_0;
    lstm_cell_kernel<false, false><<<grid, blk, 0, stream>>>(
        nullptr, nullptr, h2p, sdWhh, nullptr, nullptr,
        biasd, c2, hd0, hf0);
    out_proj<<<BDIM, 64, 0, stream>>>(hf0, oW, ob, out, 0);
    short *dp = hd0, *dn = hd1;
    float *fp = hf0, *fn = hf1;
    for (int f = 1; f < FUT; ++f) {
        lstm_cell_kernel<false, false><<<grid, blk, 0, stream>>>(
            nullptr, nullptr, dp, sWsum, nullptr, nullptr,
            biasd, c2, dn, fn);
        out_proj<<<BDIM, 64, 0, stream>>>(fn, oW, ob, out, f);
        short* tt = dp; dp = dn; dn = tt;
        float* tf = fp; fp = fn; fn = tf;
    }
}